// Round 1
// baseline (519.731 us; speedup 1.0000x reference)
//
#include <hip/hip_runtime.h>

typedef unsigned short ushort_t;
typedef __attribute__((ext_vector_type(4))) float f32x4;
typedef __attribute__((ext_vector_type(8))) short short8;
typedef __attribute__((ext_vector_type(4))) unsigned short us4;

#define D_MODEL 1024
#define NHEAD 16
#define DK 64
#define BATCH 2
#define SEQ 2048
#define MTOT (BATCH * SEQ)   // 4096

#define MFMA16(a, b, c) __builtin_amdgcn_mfma_f32_16x16x32_bf16((a), (b), (c), 0, 0, 0)

__device__ __forceinline__ ushort_t f2bf(float f) {
    union { float f; unsigned u; } c; c.f = f;
    unsigned u = c.u;
    unsigned r = u + 0x7FFFu + ((u >> 16) & 1u);   // RNE
    return (ushort_t)(r >> 16);
}

__device__ __forceinline__ void gload16(const ushort_t* g, ushort_t* l) {
    // global -> LDS direct, 16B per lane; LDS dest = wave-uniform base + lane*16
    __builtin_amdgcn_global_load_lds(
        (const __attribute__((address_space(1))) unsigned int*)g,
        (__attribute__((address_space(3))) unsigned int*)l,
        16, 0, 0);
}

// ---------------------------------------------------------------- cast f32 -> bf16
__global__ void cast_f32_bf16(const float* __restrict__ x, ushort_t* __restrict__ y, int n4) {
    int i = blockIdx.x * blockDim.x + threadIdx.x;
    int st = gridDim.x * blockDim.x;
    for (; i < n4; i += st) {
        f32x4 v = ((const f32x4*)x)[i];
        us4 o;
        o[0] = f2bf(v[0]); o[1] = f2bf(v[1]); o[2] = f2bf(v[2]); o[3] = f2bf(v[3]);
        ((us4*)y)[i] = o;
    }
}

// ---------------------------------------------------------------- GEMM  C[m,n] = (sum_k A[m,k]*B[n,k] + bias[n]) * scale
// A: [M,K] bf16 row-major, B: [N,K] bf16 row-major (i.e. X @ W^T with W stored [out,in])
// 128x128 tile, BK=32, 4 waves, each wave 64x64 (4x4 of 16x16x32 MFMA). m97-style.
__global__ __launch_bounds__(256, 2)
void gemm_bt(const ushort_t* __restrict__ A, const ushort_t* __restrict__ Bm,
             const float* __restrict__ bias, float scale,
             int M, int N, int K, ushort_t* Cb, float* Cf) {
    __shared__ ushort_t As[128 * 32];
    __shared__ ushort_t Bs[128 * 32];
    const int tid  = threadIdx.x;
    const int lane = tid & 63;
    const int wid  = tid >> 6;
    const int nbn  = N >> 7;
    const int bm   = blockIdx.x / nbn;
    const int bn   = blockIdx.x % nbn;
    const int row0 = bm << 7;
    const int col0 = bn << 7;
    const int wrow = (wid >> 1) << 6;   // 0 or 64
    const int wcol = (wid & 1) << 6;    // 0 or 64

    f32x4 acc[4][4];
    for (int i = 0; i < 4; i++)
        for (int j = 0; j < 4; j++)
            acc[i][j] = (f32x4){0.f, 0.f, 0.f, 0.f};

    const int l4 = lane >> 2;           // row within 16-row staging group
    const int lc = (lane & 3) << 3;     // k elem offset (0,8,16,24)
    const int lr = lane & 15;
    const int ko = (lane >> 4) << 3;

    for (int k0 = 0; k0 < K; k0 += 32) {
        // stage A tile rows [row0..row0+127], k0..k0+31 ; wave w covers rows 32w..32w+31
        gload16(A + (size_t)(row0 + 32 * wid + l4) * K + k0 + lc,      As + (2 * wid + 0) * 512);
        gload16(A + (size_t)(row0 + 32 * wid + 16 + l4) * K + k0 + lc, As + (2 * wid + 1) * 512);
        gload16(Bm + (size_t)(col0 + 32 * wid + l4) * K + k0 + lc,      Bs + (2 * wid + 0) * 512);
        gload16(Bm + (size_t)(col0 + 32 * wid + 16 + l4) * K + k0 + lc, Bs + (2 * wid + 1) * 512);
        __syncthreads();

        short8 af[4], bfr[4];
        for (int i = 0; i < 4; i++)
            af[i] = *(const short8*)(As + (wrow + i * 16 + lr) * 32 + ko);
        for (int j = 0; j < 4; j++)
            bfr[j] = *(const short8*)(Bs + (wcol + j * 16 + lr) * 32 + ko);
        for (int i = 0; i < 4; i++)
            for (int j = 0; j < 4; j++)
                acc[i][j] = MFMA16(af[i], bfr[j], acc[i][j]);
        __syncthreads();
    }

    // epilogue: row = (lane>>4)*4 + r, col = lane&15  (verified C/D layout)
    for (int i = 0; i < 4; i++)
        for (int j = 0; j < 4; j++) {
            int m = row0 + wrow + i * 16 + ((lane >> 4) << 2);
            int n = col0 + wcol + j * 16 + (lane & 15);
            float bs = bias[n];
            for (int r = 0; r < 4; r++) {
                float v = (acc[i][j][r] + bs) * scale;
                if (Cf) Cf[(size_t)(m + r) * N + n] = v;
                else    Cb[(size_t)(m + r) * N + n] = f2bf(v);
            }
        }
}

// ---------------------------------------------------------------- flash attention
// grid (SEQ/128, B*H); block 256 (4 waves). Wave handles 32 q-rows (2x 16-row MFMA tiles).
// KVBLK=64. Online softmax (scale already folded into Q projection).
__global__ __launch_bounds__(256, 2)
void attn_fwd(const ushort_t* __restrict__ Qp, const ushort_t* __restrict__ Kp,
              const ushort_t* __restrict__ Vp, ushort_t* __restrict__ ctx) {
    __shared__ ushort_t Ks[64 * 72];    // padded rows: +16B to break bank conflicts
    __shared__ ushort_t Vt[64 * 72];    // V transposed: Vt[d][k]
    __shared__ ushort_t Ps[128 * 72];   // P tile bf16

    const int tid  = threadIdx.x;
    const int lane = tid & 63;
    const int wid  = tid >> 6;
    const int b    = blockIdx.y >> 4;
    const int h    = blockIdx.y & 15;
    const size_t base = ((size_t)b * SEQ) * D_MODEL + h * DK;
    const int qrow0 = blockIdx.x * 128 + wid * 32;

    const int lr = lane & 15;
    const int ko = (lane >> 4) << 3;    // k-elem offset within 32 (0,8,16,24)
    const int rr4 = (lane >> 4) << 2;   // C-layout row group

    // Q fragments in registers (hoisted once)
    short8 qa[2][2];
    for (int t = 0; t < 2; t++)
        for (int s = 0; s < 2; s++)
            qa[t][s] = *(const short8*)(Qp + base + (size_t)(qrow0 + t * 16 + lr) * D_MODEL + s * 32 + ko);

    f32x4 o[2][4];
    float run_m[2][4], run_l[2][4];
    for (int t = 0; t < 2; t++)
        for (int j = 0; j < 4; j++) {
            o[t][j] = (f32x4){0.f, 0.f, 0.f, 0.f};
            run_m[t][j & 3] = -1e30f;
            run_l[t][j & 3] = 0.f;
        }

    for (int kv0 = 0; kv0 < SEQ; kv0 += 64) {
        // ---- stage K (row-major, padded) and V (transposed, padded)
        for (int cc = tid; cc < 512; cc += 256) {
            int r = cc >> 3, e = (cc & 7) << 3;
            short8 kvv = *(const short8*)(Kp + base + (size_t)(kv0 + r) * D_MODEL + e);
            *(short8*)(Ks + r * 72 + e) = kvv;
        }
        {
            int vk = tid & 63, vd0 = (tid >> 6) << 4;
            short8 v0 = *(const short8*)(Vp + base + (size_t)(kv0 + vk) * D_MODEL + vd0);
            short8 v1 = *(const short8*)(Vp + base + (size_t)(kv0 + vk) * D_MODEL + vd0 + 8);
            for (int j = 0; j < 8; j++) {
                Vt[(vd0 + j) * 72 + vk]     = (ushort_t)v0[j];
                Vt[(vd0 + 8 + j) * 72 + vk] = (ushort_t)v1[j];
            }
        }
        __syncthreads();

        // ---- S = Q K^T  (16 MFMA)
        short8 kb[4][2];
        for (int ct = 0; ct < 4; ct++)
            for (int ks = 0; ks < 2; ks++)
                kb[ct][ks] = *(const short8*)(Ks + (ct * 16 + lr) * 72 + ks * 32 + ko);
        f32x4 st[2][4];
        for (int t = 0; t < 2; t++)
            for (int ct = 0; ct < 4; ct++) {
                f32x4 s = (f32x4){0.f, 0.f, 0.f, 0.f};
                s = MFMA16(qa[t][0], kb[ct][0], s);
                s = MFMA16(qa[t][1], kb[ct][1], s);
                st[t][ct] = s;
            }

        // ---- online softmax; row r of tile t lives in 16 lanes (same lane>>4), reg r
        for (int t = 0; t < 2; t++)
            for (int r = 0; r < 4; r++) {
                float mx = fmaxf(fmaxf(st[t][0][r], st[t][1][r]), fmaxf(st[t][2][r], st[t][3][r]));
                for (int off = 8; off; off >>= 1) mx = fmaxf(mx, __shfl_xor(mx, off));
                float nm = fmaxf(run_m[t][r], mx);
                float corr = __expf(run_m[t][r] - nm);
                run_m[t][r] = nm;
                float rs = 0.f;
                for (int ct = 0; ct < 4; ct++) {
                    float p = __expf(st[t][ct][r] - nm);
                    st[t][ct][r] = p;
                    rs += p;
                }
                for (int off = 8; off; off >>= 1) rs += __shfl_xor(rs, off);
                run_l[t][r] = run_l[t][r] * corr + rs;
                for (int dt = 0; dt < 4; dt++) o[t][dt][r] *= corr;
            }

        // ---- P -> LDS (bf16)
        for (int t = 0; t < 2; t++)
            for (int ct = 0; ct < 4; ct++)
                for (int r = 0; r < 4; r++)
                    Ps[(wid * 32 + t * 16 + rr4 + r) * 72 + ct * 16 + lr] = f2bf(st[t][ct][r]);
        __syncthreads();

        // ---- O += P V  (16 MFMA)
        short8 vb[4][2], pa[2][2];
        for (int dt = 0; dt < 4; dt++)
            for (int ks = 0; ks < 2; ks++)
                vb[dt][ks] = *(const short8*)(Vt + (dt * 16 + lr) * 72 + ks * 32 + ko);
        for (int t = 0; t < 2; t++)
            for (int ks = 0; ks < 2; ks++)
                pa[t][ks] = *(const short8*)(Ps + (wid * 32 + t * 16 + lr) * 72 + ks * 32 + ko);
        for (int t = 0; t < 2; t++)
            for (int dt = 0; dt < 4; dt++) {
                o[t][dt] = MFMA16(pa[t][0], vb[dt][0], o[t][dt]);
                o[t][dt] = MFMA16(pa[t][1], vb[dt][1], o[t][dt]);
            }
        __syncthreads();
    }

    // ---- epilogue: ctx[b, s, h*64 + d] bf16
    for (int t = 0; t < 2; t++)
        for (int dt = 0; dt < 4; dt++)
            for (int r = 0; r < 4; r++) {
                float v = o[t][dt][r] / run_l[t][r];
                ctx[base + (size_t)(qrow0 + t * 16 + rr4 + r) * D_MODEL + dt * 16 + lr] = f2bf(v);
            }
}

// ----------------------------------------------------------------
extern "C" void kernel_launch(void* const* d_in, const int* in_sizes, int n_in,
                              void* d_out, int out_size, void* d_ws, size_t ws_size,
                              hipStream_t stream) {
    (void)in_sizes; (void)n_in; (void)out_size; (void)ws_size;
    const float* q  = (const float*)d_in[0];
    const float* k  = (const float*)d_in[1];
    const float* v  = (const float*)d_in[2];
    const float* Wq = (const float*)d_in[3];
    const float* bq = (const float*)d_in[4];
    const float* Wk = (const float*)d_in[5];
    const float* bk = (const float*)d_in[6];
    const float* Wv = (const float*)d_in[7];
    const float* bv = (const float*)d_in[8];
    const float* Wo = (const float*)d_in[9];
    const float* bo = (const float*)d_in[10];
    float* out = (float*)d_out;

    // workspace layout (bf16): Xb (reused: q,k,v cast then ctx) | Wb (reused per weight) | Qp | Kp | Vp
    ushort_t* Xb = (ushort_t*)d_ws;
    ushort_t* Wb = Xb + (size_t)MTOT * D_MODEL;
    ushort_t* Qp = Wb + (size_t)D_MODEL * D_MODEL;
    ushort_t* Kp = Qp + (size_t)MTOT * D_MODEL;
    ushort_t* Vp = Kp + (size_t)MTOT * D_MODEL;

    const int n4x = MTOT * D_MODEL / 4;
    const int n4w = D_MODEL * D_MODEL / 4;
    const dim3 blk(256);
    const dim3 ggrid((MTOT / 128) * (D_MODEL / 128));
    const float scaleQ = 0.125f;   // 1/sqrt(dk) folded into Q projection (bias included: (x@W+b)/8)

    // Q projection
    cast_f32_bf16<<<2048, blk, 0, stream>>>(q, Xb, n4x);
    cast_f32_bf16<<<1024, blk, 0, stream>>>(Wq, Wb, n4w);
    gemm_bt<<<ggrid, blk, 0, stream>>>(Xb, Wb, bq, scaleQ, MTOT, D_MODEL, D_MODEL, Qp, nullptr);
    // K projection
    cast_f32_bf16<<<2048, blk, 0, stream>>>(k, Xb, n4x);
    cast_f32_bf16<<<1024, blk, 0, stream>>>(Wk, Wb, n4w);
    gemm_bt<<<ggrid, blk, 0, stream>>>(Xb, Wb, bk, 1.0f, MTOT, D_MODEL, D_MODEL, Kp, nullptr);
    // V projection
    cast_f32_bf16<<<2048, blk, 0, stream>>>(v, Xb, n4x);
    cast_f32_bf16<<<1024, blk, 0, stream>>>(Wv, Wb, n4w);
    gemm_bt<<<ggrid, blk, 0, stream>>>(Xb, Wb, bv, 1.0f, MTOT, D_MODEL, D_MODEL, Vp, nullptr);
    // attention -> ctx (bf16) into Xb
    attn_fwd<<<dim3(SEQ / 128, BATCH * NHEAD), blk, 0, stream>>>(Qp, Kp, Vp, Xb);
    // output projection -> fp32 d_out
    cast_f32_bf16<<<1024, blk, 0, stream>>>(Wo, Wb, n4w);
    gemm_bt<<<ggrid, blk, 0, stream>>>(Xb, Wb, bo, 1.0f, MTOT, D_MODEL, D_MODEL, nullptr, out);
}

// Round 3
// 186.071 us; speedup vs baseline: 2.7932x; 2.7932x over previous
//
#include <hip/hip_runtime.h>

typedef unsigned short ushort_t;
typedef __attribute__((ext_vector_type(4))) float f32x4;
typedef __attribute__((ext_vector_type(8))) short short8;
typedef __attribute__((ext_vector_type(4))) unsigned short us4;

#define D_MODEL 1024
#define NHEAD 16
#define DK 64
#define BATCH 2
#define SEQ 2048
#define MTOT 4096
#define EX (MTOT * D_MODEL)      // 4,194,304 elems
#define EW (D_MODEL * D_MODEL)   // 1,048,576 elems

#define MFMA16(a,b,c) __builtin_amdgcn_mfma_f32_16x16x32_bf16((a),(b),(c),0,0,0)

__device__ __forceinline__ ushort_t f2bf(float f){
    union{float f;unsigned u;}c; c.f=f;
    unsigned u=c.u, r=u+0x7FFFu+((u>>16)&1u);   // RNE
    return (ushort_t)(r>>16);
}
__device__ __forceinline__ void gload16(const ushort_t* g, ushort_t* l){
    __builtin_amdgcn_global_load_lds((const __attribute__((address_space(1))) unsigned*)g,
                                     (__attribute__((address_space(3))) unsigned*)l, 16, 0, 0);
}
// bijective XCD swizzle (nwg % 8 == 0): dispatch slot -> work id; each XCD gets a contiguous work chunk
__device__ __forceinline__ int xcd_swz(int nwg){
    int s = blockIdx.x;
    return (s & 7) * (nwg >> 3) + (s >> 3);
}

// ---------------------------------------------------------------- casts
__global__ void cast1(const float* __restrict__ x, ushort_t* __restrict__ y, int n4){
    int i = blockIdx.x*blockDim.x + threadIdx.x, st = gridDim.x*blockDim.x;
    for(; i < n4; i += st){
        f32x4 v = ((const f32x4*)x)[i];
        us4 o; o[0]=f2bf(v[0]); o[1]=f2bf(v[1]); o[2]=f2bf(v[2]); o[3]=f2bf(v[3]);
        ((us4*)y)[i] = o;
    }
}
__global__ void cast3(const float* __restrict__ a, const float* __restrict__ b,
                      const float* __restrict__ c, ushort_t* __restrict__ dst, int n4){
    const float* s = blockIdx.y==0 ? a : (blockIdx.y==1 ? b : c);
    us4* d = (us4*)(dst + (size_t)blockIdx.y * n4 * 4);
    const f32x4* sv = (const f32x4*)s;
    int i = blockIdx.x*blockDim.x + threadIdx.x, st = gridDim.x*blockDim.x;
    for(; i < n4; i += st){
        f32x4 v = sv[i];
        us4 o; o[0]=f2bf(v[0]); o[1]=f2bf(v[1]); o[2]=f2bf(v[2]); o[3]=f2bf(v[3]);
        d[i] = o;
    }
}

// ---------------------------------------------------------------- GEMM body
// C[m,n] = (sum_k A[m,k]*B[n,k] + bias[n]) * scale ; M=4096, N=K=1024 fixed.
// 128x128 tile, BK=32, 4 waves, 2-phase double-buffered LDS pipeline.
// mode 0: bf16 [M][N] ; mode 1: bf16 V-transposed [b][h][d][s] ; mode 2: fp32 [M][N]
__device__ __forceinline__ void gemm_body(
    const ushort_t* __restrict__ A, const ushort_t* __restrict__ Bm,
    const float* __restrict__ bias, float scale, int bm, int bn, int mode,
    void* __restrict__ out,
    ushort_t* As0, ushort_t* As1, ushort_t* Bs0, ushort_t* Bs1)
{
    const int tid = threadIdx.x, lane = tid & 63, wid = tid >> 6;
    const int row0 = bm << 7, col0 = bn << 7;
    const int wrow = (wid >> 1) << 6, wcol = (wid & 1) << 6;
    const int l4 = lane >> 2, lc = (lane & 3) << 3, lr = lane & 15, ko = (lane >> 4) << 3;
    const f32x4 Z4 = {0.f,0.f,0.f,0.f};

    f32x4 acc[4][4];
#pragma unroll
    for(int i=0;i<4;i++)
#pragma unroll
        for(int j=0;j<4;j++) acc[i][j] = Z4;

#define GSTAGE(AS,BS,k0) do{ \
    gload16(A +(size_t)(row0+32*wid   +l4)*D_MODEL+(k0)+lc, (AS)+(2*wid  )*512); \
    gload16(A +(size_t)(row0+32*wid+16+l4)*D_MODEL+(k0)+lc, (AS)+(2*wid+1)*512); \
    gload16(Bm+(size_t)(col0+32*wid   +l4)*D_MODEL+(k0)+lc, (BS)+(2*wid  )*512); \
    gload16(Bm+(size_t)(col0+32*wid+16+l4)*D_MODEL+(k0)+lc, (BS)+(2*wid+1)*512); \
}while(0)
#define GCOMP(AS,BS) do{ \
    short8 af[4], bf[4]; \
    _Pragma("unroll") for(int i=0;i<4;i++) af[i]=*(const short8*)((AS)+(wrow+i*16+lr)*32+ko); \
    _Pragma("unroll") for(int j=0;j<4;j++) bf[j]=*(const short8*)((BS)+(wcol+j*16+lr)*32+ko); \
    _Pragma("unroll") for(int i=0;i<4;i++) \
    _Pragma("unroll") for(int j=0;j<4;j++) acc[i][j]=MFMA16(af[i],bf[j],acc[i][j]); \
}while(0)

    GSTAGE(As0,Bs0,0);
    __syncthreads();                       // barrier drains vmcnt: tile0 ready
#pragma unroll 1
    for(int t=0; t<32; t+=2){
        if(t+1<32) GSTAGE(As1,Bs1,(t+1)*32);   // issue next while computing current
        GCOMP(As0,Bs0);
        __syncthreads();                       // drain: As1 staged, As0 free
        if(t+2<32) GSTAGE(As0,Bs0,(t+2)*32);
        GCOMP(As1,Bs1);
        __syncthreads();
    }
#undef GSTAGE
#undef GCOMP

    const int rr4 = (lane >> 4) << 2;
#pragma unroll
    for(int i=0;i<4;i++){
#pragma unroll
        for(int j=0;j<4;j++){
            const int m0 = row0 + wrow + i*16 + rr4;
            const int n  = col0 + wcol + j*16 + lr;
            const float bs = bias[n];
            if(mode == 2){
                float* O = (float*)out;
#pragma unroll
                for(int r=0;r<4;r++) O[(size_t)(m0+r)*D_MODEL+n] = (acc[i][j][r]+bs)*scale;
            } else if(mode == 0){
                ushort_t* O = (ushort_t*)out;
#pragma unroll
                for(int r=0;r<4;r++) O[(size_t)(m0+r)*D_MODEL+n] = f2bf((acc[i][j][r]+bs)*scale);
            } else {
                // V transposed: Vt[b][h][d][s], s = m&2047 consecutive over r -> one 8B store
                ushort_t* O = (ushort_t*)out;
                const int bb = m0 >> 11, s = m0 & 2047, h = n >> 6, d = n & 63;
                us4 p;
#pragma unroll
                for(int r=0;r<4;r++) p[r] = f2bf((acc[i][j][r]+bs)*scale);
                *(us4*)(O + ((size_t)(bb*NHEAD + h)*DK + d)*SEQ + s) = p;
            }
        }
    }
}

__global__ __launch_bounds__(256,2)
void qkv_fused(const ushort_t* __restrict__ Xq, const ushort_t* __restrict__ Xk,
               const ushort_t* __restrict__ Xv,
               const ushort_t* __restrict__ Wq, const ushort_t* __restrict__ Wk,
               const ushort_t* __restrict__ Wv,
               const float* __restrict__ bq, const float* __restrict__ bk,
               const float* __restrict__ bv,
               ushort_t* Qp, ushort_t* Kp, ushort_t* VtG)
{
    __shared__ ushort_t As0[4096], As1[4096], Bs0[4096], Bs1[4096];
    const int wk = xcd_swz(768);
    const int which = wk >> 8, t = wk & 255;
    const ushort_t *A, *Bm; const float* bias; float scale; int mode; void* out;
    if(which == 0){ A=Xq; Bm=Wq; bias=bq; scale=0.125f; mode=0; out=Qp; }       // 1/sqrt(dk) folded
    else if(which == 1){ A=Xk; Bm=Wk; bias=bk; scale=1.f; mode=0; out=Kp; }
    else { A=Xv; Bm=Wv; bias=bv; scale=1.f; mode=1; out=VtG; }
    gemm_body(A,Bm,bias,scale, t>>3, t&7, mode, out, As0,As1,Bs0,Bs1);
}

__global__ __launch_bounds__(256,2)
void gemm_one(const ushort_t* __restrict__ A, const ushort_t* __restrict__ Bm,
              const float* __restrict__ bias, float scale, int mode, void* out)
{
    __shared__ ushort_t As0[4096], As1[4096], Bs0[4096], Bs1[4096];
    const int wk = xcd_swz(256);
    gemm_body(A,Bm,bias,scale, wk>>3, wk&7, mode, out, As0,As1,Bs0,Bs1);
}

// ---------------------------------------------------------------- flash attention
// grid 1024 (32 bh * 32 q-tiles, XCD-swizzled). Block 256 = 4 waves, wave = 16 q-rows.
// K staged [64][64] XOR-swizzled via global_load_lds; V pre-transposed in global, staged same way.
// P wave-private in LDS (no barrier between P write and read).
__global__ __launch_bounds__(256,4)
void attn_fwd(const ushort_t* __restrict__ Qp, const ushort_t* __restrict__ Kp,
              const ushort_t* __restrict__ VtG, ushort_t* __restrict__ ctx)
{
    __shared__ ushort_t Ks[64*64];
    __shared__ ushort_t Vs[64*64];
    __shared__ ushort_t Ps[64*72];

    const int wk = xcd_swz(1024);
    const int bh = wk >> 5, qt = wk & 31;
    const int b = bh >> 4, h = bh & 15;
    const int tid = threadIdx.x, lane = tid & 63, wid = tid >> 6;
    const int lq = lane & 15, hi = lane >> 4;
    const size_t qkbase = (size_t)b*SEQ*D_MODEL + h*DK;
    const size_t vbase  = (size_t)bh * DK * SEQ;
    const int q0 = qt*64 + wid*16;
    const f32x4 Z4 = {0.f,0.f,0.f,0.f};

    // Q fragments (A-operand): lane row = lq, d-elems hi*8 within each 32-slice
    short8 qa[2];
#pragma unroll
    for(int ks=0;ks<2;ks++)
        qa[ks] = *(const short8*)(Qp + qkbase + (size_t)(q0+lq)*D_MODEL + ks*32 + hi*8);

    f32x4 o[4];
    float run_m[4], run_l[4];
#pragma unroll
    for(int r=0;r<4;r++){ o[r]=Z4; run_m[r]=-1e30f; run_l[r]=0.f; }

    const int rsub = lane >> 3;            // 0..7
    const int jsw  = (lane & 7) ^ rsub;    // inverse-swizzled source chunk

#pragma unroll 1
    for(int kv0=0; kv0<SEQ; kv0+=64){
        // ---- stage K rows [wid*16,+16) and Vt rows (d) [wid*16,+16), swizzled source
#pragma unroll
        for(int c=0;c<2;c++){
            const int r = wid*16 + c*8 + rsub;          // r&7 == rsub
            gload16(Kp  + qkbase + (size_t)(kv0+r)*D_MODEL + jsw*8, Ks + (wid*16+c*8)*64);
            gload16(VtG + vbase  + (size_t)r*SEQ + kv0 + jsw*8,     Vs + (wid*16+c*8)*64);
        }
        __syncthreads();

        // ---- S = Q K^T : B-frag row = ct*16+lq (k), chunk (ks*4+hi)^(lq&7)
        f32x4 st[4];
#pragma unroll
        for(int ct=0;ct<4;ct++){
            short8 k0 = *(const short8*)(Ks + (ct*16+lq)*64 + (((0+hi)^(lq&7))<<3));
            short8 k1 = *(const short8*)(Ks + (ct*16+lq)*64 + (((4+hi)^(lq&7))<<3));
            f32x4 s = MFMA16(qa[0], k0, Z4);
            st[ct]  = MFMA16(qa[1], k1, s);
        }

        // ---- online softmax; lane holds S[q=hi*4+r][k=ct*16+lq]; reduce over lq (DPP xor 1..8)
#pragma unroll
        for(int r=0;r<4;r++){
            float mx = fmaxf(fmaxf(st[0][r],st[1][r]), fmaxf(st[2][r],st[3][r]));
#pragma unroll
            for(int off=8;off>=1;off>>=1) mx = fmaxf(mx, __shfl_xor(mx,off));
            const float nm = fmaxf(run_m[r], mx);
            const float corr = __expf(run_m[r] - nm);
            run_m[r] = nm;
            float rs = 0.f;
#pragma unroll
            for(int ct=0;ct<4;ct++){
                float p = __expf(st[ct][r] - nm);
                st[ct][r] = p; rs += p;
            }
#pragma unroll
            for(int off=8;off>=1;off>>=1) rs += __shfl_xor(rs,off);
            run_l[r] = run_l[r]*corr + rs;
#pragma unroll
            for(int dt=0;dt<4;dt++) o[dt][r] *= corr;
        }

        // ---- P -> LDS (wave-private rows; same-wave RAW ordered by lgkmcnt)
#pragma unroll
        for(int ct=0;ct<4;ct++)
#pragma unroll
            for(int r=0;r<4;r++)
                Ps[(wid*16 + hi*4 + r)*72 + ct*16 + lq] = f2bf(st[ct][r]);

        // ---- O += P V : A-frag P rows lq, B-frag Vt rows d=dt*16+lq (swizzled chunks)
        short8 pa0 = *(const short8*)(Ps + (wid*16+lq)*72 + hi*8);
        short8 pa1 = *(const short8*)(Ps + (wid*16+lq)*72 + 32 + hi*8);
#pragma unroll
        for(int dt=0;dt<4;dt++){
            short8 v0 = *(const short8*)(Vs + (dt*16+lq)*64 + (((0+hi)^(lq&7))<<3));
            short8 v1 = *(const short8*)(Vs + (dt*16+lq)*64 + (((4+hi)^(lq&7))<<3));
            o[dt] = MFMA16(pa0, v0, o[dt]);
            o[dt] = MFMA16(pa1, v1, o[dt]);
        }
        __syncthreads();    // all waves done reading Ks/Vs before restage
    }

    // ---- epilogue: ctx[b][s][h*64+d] bf16
    float inv[4];
#pragma unroll
    for(int r=0;r<4;r++) inv[r] = 1.f/run_l[r];
#pragma unroll
    for(int dt=0;dt<4;dt++)
#pragma unroll
        for(int r=0;r<4;r++)
            ctx[qkbase + (size_t)(q0 + hi*4 + r)*D_MODEL + dt*16 + lq] = f2bf(o[dt][r]*inv[r]);
}

// ----------------------------------------------------------------
extern "C" void kernel_launch(void* const* d_in, const int* in_sizes, int n_in,
                              void* d_out, int out_size, void* d_ws, size_t ws_size,
                              hipStream_t stream) {
    (void)in_sizes; (void)n_in; (void)out_size;
    const float* q  = (const float*)d_in[0];
    const float* k  = (const float*)d_in[1];
    const float* v  = (const float*)d_in[2];
    const float* Wq = (const float*)d_in[3];
    const float* bq = (const float*)d_in[4];
    const float* Wk = (const float*)d_in[5];
    const float* bk = (const float*)d_in[6];
    const float* Wv = (const float*)d_in[7];
    const float* bv = (const float*)d_in[8];
    const float* Wo = (const float*)d_in[9];
    const float* bo = (const float*)d_in[10];
    float* out = (float*)d_out;

    ushort_t* WS = (ushort_t*)d_ws;
    const dim3 blk(256);
    const int n4x = EX/4, n4w = EW/4;

    if(ws_size >= (size_t)(6*(size_t)EX + 3*(size_t)EW) * 2){
        // tier A: fused QKV (3 blocks/CU)
        ushort_t* Xq  = WS;
        ushort_t* Xk  = Xq + EX;
        ushort_t* Xv  = Xk + EX;
        ushort_t* Wqb = Xv + EX;
        ushort_t* Wkb = Wqb + EW;
        ushort_t* Wvb = Wkb + EW;
        ushort_t* Qp  = Wvb + EW;
        ushort_t* Kp  = Qp + EX;
        ushort_t* VtG = Kp + EX;
        ushort_t* ctx = Xq;     // free after qkv_fused
        ushort_t* Wob = Wqb;    // free after qkv_fused

        cast3<<<dim3(1024,3), blk, 0, stream>>>(q, k, v, Xq, n4x);
        cast3<<<dim3(256,3),  blk, 0, stream>>>(Wq, Wk, Wv, Wqb, n4w);
        qkv_fused<<<768, blk, 0, stream>>>(Xq,Xk,Xv, Wqb,Wkb,Wvb, bq,bk,bv, Qp,Kp,VtG);
        cast1<<<512, blk, 0, stream>>>(Wo, Wob, n4w);
        attn_fwd<<<1024, blk, 0, stream>>>(Qp, Kp, VtG, ctx);
        gemm_one<<<256, blk, 0, stream>>>(ctx, Wob, bo, 1.f, 2, out);
    } else {
        // tier C: sequential, 35.6 MB (proven size)
        ushort_t* Xb  = WS;
        ushort_t* Wb  = Xb + EX;
        ushort_t* Qp  = Wb + EW;
        ushort_t* Kp  = Qp + EX;
        ushort_t* VtG = Kp + EX;
        ushort_t* ctx = Xb;

        cast1<<<1024, blk, 0, stream>>>(q, Xb, n4x);
        cast1<<<512,  blk, 0, stream>>>(Wq, Wb, n4w);
        gemm_one<<<256, blk, 0, stream>>>(Xb, Wb, bq, 0.125f, 0, Qp);
        cast1<<<1024, blk, 0, stream>>>(k, Xb, n4x);
        cast1<<<512,  blk, 0, stream>>>(Wk, Wb, n4w);
        gemm_one<<<256, blk, 0, stream>>>(Xb, Wb, bk, 1.f, 0, Kp);
        cast1<<<1024, blk, 0, stream>>>(v, Xb, n4x);
        cast1<<<512,  blk, 0, stream>>>(Wv, Wb, n4w);
        gemm_one<<<256, blk, 0, stream>>>(Xb, Wb, bv, 1.f, 1, VtG);
        attn_fwd<<<1024, blk, 0, stream>>>(Qp, Kp, VtG, ctx);
        cast1<<<512, blk, 0, stream>>>(Wo, Wb, n4w);
        gemm_one<<<256, blk, 0, stream>>>(ctx, Wb, bo, 1.f, 2, out);
    }
}